// Round 13
// baseline (380.199 us; speedup 1.0000x reference)
//
#include <hip/hip_runtime.h>
#include <hip/hip_bf16.h>
#include <math.h>

// Problem constants
// N=64, L=1024, C_IN=514, NOISE_C=64, COMP=16, NC=3, MAIN_C=80
// P = N*L = 65536 positions

__device__ __forceinline__ float lrelu(float x){ return fmaxf(x, 0.2f*x); }

// ---------------------------------------------------------------------------
// K_init: fused weight transposes + positional encoding.
__global__ void k_init(const float* __restrict__ ew1, const float* __restrict__ ew2,
                       const float* __restrict__ w3,  const float* __restrict__ w4,
                       float* __restrict__ wT1, float* __restrict__ wT2,
                       float* __restrict__ wT3, float* __restrict__ wT4,
                       float* __restrict__ pe){
  int i = blockIdx.x*256 + threadIdx.x;
  if (i < 16448){
    int c = i>>5, oc = i&31;
    wT1[i] = ew1[oc*514 + c];
  } else if (i < 16448+1536){
    int j = i - 16448; int oc = j%16; int t = j/16; int dl = t%3; int ic = t/3;
    wT2[j] = ew2[(oc*32+ic)*3 + dl];
  } else if (i < 16448+1536+26880){
    int j = i - 17984; int oc = j%48; int t = j/48; int dl = t%7; int ic = t/7;
    wT3[j] = w3[(oc*80+ic)*7 + dl];
  } else if (i < 46592){
    int j = i - 44864; int oc = j%12; int t = j/12; int dl = t%3; int ic = t/3;
    wT4[j] = w4[(oc*48+ic)*3 + dl];
  } else if (i < 46592 + 80*1024){
    int j = i - 46592;
    int ch = j >> 10, l = j & 1023;
    double dv = 1.0 / pow(10000.0, (2.0*(double)(ch>>1)) / 80.0);
    double ang = dv * (double)l;
    pe[j] = (float)((ch & 1) ? cos(ang) : sin(ang));
  }
}

// ---------------------------------------------------------------------------
// K1 v3: pointwise conv 514->32 + bias + lrelu.  x1[p][32]
__global__ __launch_bounds__(256) void k_conv1(const float* __restrict__ A,
    const float* __restrict__ wT1, const float* __restrict__ eb1,
    float* __restrict__ x1){
  __shared__ float red[32][256];           // [c][s*64 + pos] : 32 KB
  const int tid = threadIdx.x;
  const int pl  = tid & 63;                // position within block
  const int s   = __builtin_amdgcn_readfirstlane(tid >> 6);   // split id
  const int p   = blockIdx.x*64 + pl;

  const int c0 = (s == 0) ? 0 : 130 + (s-1)*128;
  const int c1 = (s == 0) ? 130 : 130 + s*128;

  const float* row = A + (size_t)p*514;
  float acc[32];
  #pragma unroll
  for (int j=0;j<32;j++) acc[j]=0.f;

  #pragma unroll 8
  for (int c=c0;c<c1;c+=2){
    float2 v = *reinterpret_cast<const float2*>(row + c);
    const float* w = wT1 + (size_t)c*32;
    #pragma unroll
    for (int j=0;j<32;j++) acc[j] = fmaf(v.x, w[j],    acc[j]);
    #pragma unroll
    for (int j=0;j<32;j++) acc[j] = fmaf(v.y, w[32+j], acc[j]);
  }

  #pragma unroll
  for (int j=0;j<32;j++) red[j][s*64 + pl] = acc[j];
  __syncthreads();

  float out[8];
  #pragma unroll
  for (int j=0;j<8;j++){
    const int c = s*8 + j;
    float v = (red[c][pl] + red[c][64+pl]) + (red[c][128+pl] + red[c][192+pl]);
    out[j] = lrelu(v + eb1[c]);
  }
  float* dst = x1 + ((size_t)(blockIdx.x*64 + pl))*32 + s*8;
  *(float4*)(dst  ) = make_float4(out[0],out[1],out[2],out[3]);
  *(float4*)(dst+4) = make_float4(out[4],out[5],out[6],out[7]);
}

// ---------------------------------------------------------------------------
// K2: conv k=3, 32->16 (+bias, no act), y2[p][16], and per-block BN partials.
__global__ __launch_bounds__(256) void k_conv2(const float* __restrict__ x1,
    const float* __restrict__ wT2, const float* __restrict__ eb2,
    float* __restrict__ y2, float* __restrict__ part){
  __shared__ float xt[32][264];
  const int tid = threadIdx.x, lane = tid & 63;
  const int wv = __builtin_amdgcn_readfirstlane(tid >> 6);
  const int n = blockIdx.x >> 2, base = (blockIdx.x & 3)*256;

  for (int r = tid; r < 264; r += 256){
    int l = base - 4 + r;
    if (l >= 0 && l < 1024){
      const float* src = x1 + ((size_t)n*1024 + l)*32;
      #pragma unroll
      for (int c=0;c<32;c+=4){
        float4 v = *(const float4*)(src + c);
        xt[c][r]=v.x; xt[c+1][r]=v.y; xt[c+2][r]=v.z; xt[c+3][r]=v.w;
      }
    } else {
      #pragma unroll
      for (int c=0;c<32;c++) xt[c][r] = 0.f;
    }
  }
  __syncthreads();

  const int og = wv*4;
  const int j0 = 4*lane;
  float acc[4][4];
  #pragma unroll
  for (int j=0;j<4;j++){
    #pragma unroll
    for (int p=0;p<4;p++) acc[j][p]=0.f;
  }
  for (int ic=0; ic<32; ic++){
    float xr[12];
    #pragma unroll
    for (int u=0;u<12;u+=4){
      float4 v = *(const float4*)&xt[ic][j0+u];
      xr[u]=v.x; xr[u+1]=v.y; xr[u+2]=v.z; xr[u+3]=v.w;
    }
    const float* wrow = wT2 + ic*48 + og;   // (ic*3+dl)*16 + og
    #pragma unroll
    for (int dl=0;dl<3;dl++){
      #pragma unroll
      for (int j=0;j<4;j++){
        float w = wrow[dl*16 + j];
        #pragma unroll
        for (int p=0;p<4;p++)
          acc[j][p] = fmaf(xr[p+dl+3], w, acc[j][p]);
      }
    }
  }
  float s[4], q[4];
  #pragma unroll
  for (int j=0;j<4;j++){ s[j]=0.f; q[j]=0.f; }
  const int l0 = base + 4*lane;
  #pragma unroll
  for (int p=0;p<4;p++){
    float vv[4];
    #pragma unroll
    for (int j=0;j<4;j++){
      float val = acc[j][p] + eb2[og+j];
      vv[j]=val; s[j]+=val; q[j]+=val*val;
    }
    *(float4*)(y2 + ((size_t)n*1024 + l0 + p)*16 + og) = make_float4(vv[0],vv[1],vv[2],vv[3]);
  }
  #pragma unroll
  for (int off=32; off; off>>=1){
    #pragma unroll
    for (int j=0;j<4;j++){ s[j] += __shfl_xor(s[j], off); q[j] += __shfl_xor(q[j], off); }
  }
  if (lane == 0){
    #pragma unroll
    for (int j=0;j<4;j++){
      part[((size_t)blockIdx.x*16 + og + j)*2    ] = s[j];
      part[((size_t)blockIdx.x*16 + og + j)*2 + 1] = q[j];
    }
  }
}

// ---------------------------------------------------------------------------
// K3 v2: conv k=7, 80->48 + bias + lrelu, with gi construction fused in.
__global__ __launch_bounds__(256) void k_conv3(const float* __restrict__ y2,
    const float* __restrict__ noise, const float* __restrict__ pe,
    const float* __restrict__ bn2p, const float* __restrict__ eg,
    const float* __restrict__ ebt,
    const float* __restrict__ wT3, const float* __restrict__ b3,
    float* __restrict__ h3, float* __restrict__ cond_out){
  __shared__ float xt[80][72];             // 23 KB
  __shared__ double pS[16][16], pQ[16][16];
  __shared__ float ssh[32];
  const int tid = threadIdx.x, lane = tid & 63;
  const int og = __builtin_amdgcn_readfirstlane(tid >> 6) * 12;
  const int n = blockIdx.x >> 4, base = (blockIdx.x & 15)*64;

  // inline BN2 stats (fixed-order fp64, identical in every block)
  {
    int c = tid & 15, chunk = tid >> 4;
    double S=0.0, Q=0.0;
    #pragma unroll 4
    for (int i=chunk*16; i<chunk*16+16; i++){
      S += (double)bn2p[((size_t)i*16 + c)*2];
      Q += (double)bn2p[((size_t)i*16 + c)*2 + 1];
    }
    pS[chunk][c] = S; pQ[chunk][c] = Q;
  }
  __syncthreads();
  if (tid < 16){
    double S=0.0, Q=0.0;
    #pragma unroll
    for (int k=0;k<16;k++){ S += pS[k][tid]; Q += pQ[k][tid]; }
    double mean = S / 65536.0;
    double var  = Q / 65536.0 - mean*mean;
    double sc   = (double)eg[tid] / sqrt(var + 1e-5);
    ssh[tid*2]   = (float)sc;
    ssh[tid*2+1] = (float)((double)ebt[tid] - mean*sc);
  }
  __syncthreads();

  // stage rows 0..71 (l = base-4+r), computing gi values inline
  {
    const int q = tid & 3;               // channel quarter (20 ch each)
    for (int r = tid >> 2; r < 72; r += 64){
      int l = base - 4 + r;
      bool valid = (l >= 0 && l < 1024);
      if (q == 0){
        if (valid){
          size_t p = (size_t)n*1024 + l;
          const float* ys = y2 + p*16;
          bool interior = (r >= 4 && r < 68);
          #pragma unroll
          for (int c=0;c<16;c++){
            float cv = fmaf(ys[c], ssh[2*c], ssh[2*c+1]);
            if (interior) cond_out[((size_t)n*16 + c)*1024 + l] = cv;
            xt[c][r] = cv + pe[c*1024 + l];
          }
          const float* ns = noise + p*64;
          #pragma unroll
          for (int c=0;c<4;c++)
            xt[16+c][r] = ns[c] + pe[(16+c)*1024 + l];
        } else {
          #pragma unroll
          for (int c=0;c<20;c++) xt[c][r] = 0.f;
        }
      } else {
        if (valid){
          size_t p = (size_t)n*1024 + l;
          const float* ns = noise + p*64 + (q*20 - 16);
          #pragma unroll
          for (int c=0;c<20;c++)
            xt[q*20 + c][r] = ns[c] + pe[(q*20 + c)*1024 + l];
        } else {
          #pragma unroll
          for (int c=0;c<20;c++) xt[q*20 + c][r] = 0.f;
        }
      }
    }
  }
  __syncthreads();

  // compute: output pos l = base + lane; input rows lane+1..lane+7
  float acc[12];
  #pragma unroll
  for (int j=0;j<12;j++) acc[j]=0.f;
  for (int ic=0; ic<80; ic++){
    float xr[7];
    #pragma unroll
    for (int u=0;u<7;u++) xr[u] = xt[ic][lane+1+u];
    const float* wrow = wT3 + ic*336 + og;  // (ic*7+dl)*48 + og
    #pragma unroll
    for (int dl=0;dl<7;dl++){
      #pragma unroll
      for (int j=0;j<12;j++)
        acc[j] = fmaf(xr[dl], wrow[dl*48 + j], acc[j]);
    }
  }
  {
    float v[12];
    #pragma unroll
    for (int j=0;j<12;j++) v[j] = lrelu(acc[j] + b3[og+j]);
    float* dst = h3 + ((size_t)n*1024 + base + lane)*48 + og;
    *(float4*)(dst  ) = make_float4(v[0],v[1],v[2],v[3]);
    *(float4*)(dst+4) = make_float4(v[4],v[5],v[6],v[7]);
    *(float4*)(dst+8) = make_float4(v[8],v[9],v[10],v[11]);
  }
}

// ---------------------------------------------------------------------------
// K4: conv k=3, 48->12 (+bias), y4[p][12] + BN partials.
__global__ __launch_bounds__(256) void k_conv4(const float* __restrict__ h3,
    const float* __restrict__ wT4, const float* __restrict__ b4,
    float* __restrict__ y4, float* __restrict__ part){
  __shared__ float xt[48][258];
  __shared__ float red[4][24];
  const int tid = threadIdx.x, lane = tid & 63, wv = tid >> 6;
  const int n = blockIdx.x >> 2, base = (blockIdx.x & 3)*256;

  for (int r = tid; r < 258; r += 256){
    int l = base - 1 + r;
    if (l >= 0 && l < 1024){
      const float* src = h3 + ((size_t)n*1024 + l)*48;
      #pragma unroll
      for (int c=0;c<48;c+=4){
        float4 v = *(const float4*)(src + c);
        xt[c][r]=v.x; xt[c+1][r]=v.y; xt[c+2][r]=v.z; xt[c+3][r]=v.w;
      }
    } else {
      #pragma unroll
      for (int c=0;c<48;c++) xt[c][r]=0.f;
    }
  }
  __syncthreads();

  float acc[12];
  #pragma unroll
  for (int j=0;j<12;j++) acc[j]=0.f;
  for (int ic=0; ic<48; ic++){
    float x0 = xt[ic][tid], x1v = xt[ic][tid+1], x2 = xt[ic][tid+2];
    const float* wrow = wT4 + ic*36;       // (ic*3+dl)*12
    #pragma unroll
    for (int j=0;j<12;j++){
      acc[j] = fmaf(x0,  wrow[j],      acc[j]);
      acc[j] = fmaf(x1v, wrow[12 + j], acc[j]);
      acc[j] = fmaf(x2,  wrow[24 + j], acc[j]);
    }
  }
  float s[12], q[12];
  #pragma unroll
  for (int j=0;j<12;j++){
    float v = acc[j] + b4[j];
    acc[j] = v; s[j] = v; q[j] = v*v;
  }
  {
    float* dst = y4 + ((size_t)n*1024 + base + tid)*12;
    *(float4*)(dst  ) = make_float4(acc[0],acc[1],acc[2],acc[3]);
    *(float4*)(dst+4) = make_float4(acc[4],acc[5],acc[6],acc[7]);
    *(float4*)(dst+8) = make_float4(acc[8],acc[9],acc[10],acc[11]);
  }
  #pragma unroll
  for (int off=32; off; off>>=1){
    #pragma unroll
    for (int j=0;j<12;j++){ s[j] += __shfl_xor(s[j], off); q[j] += __shfl_xor(q[j], off); }
  }
  if (lane == 0){
    #pragma unroll
    for (int j=0;j<12;j++){ red[wv][j] = s[j]; red[wv][12+j] = q[j]; }
  }
  __syncthreads();
  if (tid < 24){
    float v = red[0][tid] + red[1][tid] + red[2][tid] + red[3][tid];
    if (tid < 12) part[((size_t)blockIdx.x*12 + tid)*2] = v;
    else          part[((size_t)blockIdx.x*12 + (tid-12))*2 + 1] = v;
  }
}

// ---------------------------------------------------------------------------
// K5a v2: hflatT[j][n] = lrelu(bn(y4)), j = c*1024 + l (transposed for FC).
__global__ __launch_bounds__(256) void k_hflat(const float* __restrict__ y4,
    const float* __restrict__ bn4p, const float* __restrict__ g4,
    const float* __restrict__ bt4, float* __restrict__ hT){
  __shared__ double pS[16][12], pQ[16][12];
  __shared__ float ssh[24];
  const int tid = threadIdx.x;
  if (tid < 192){
    int c = tid % 12, chunk = tid / 12;
    double S=0.0, Q=0.0;
    #pragma unroll 4
    for (int i=chunk*16; i<chunk*16+16; i++){
      S += (double)bn4p[((size_t)i*12 + c)*2];
      Q += (double)bn4p[((size_t)i*12 + c)*2 + 1];
    }
    pS[chunk][c] = S; pQ[chunk][c] = Q;
  }
  __syncthreads();
  if (tid < 12){
    double S=0.0, Q=0.0;
    #pragma unroll
    for (int k=0;k<16;k++){ S += pS[k][tid]; Q += pQ[k][tid]; }
    double mean = S / 65536.0;
    double var  = Q / 65536.0 - mean*mean;
    double sc   = (double)g4[tid] / sqrt(var + 1e-5);
    ssh[tid*2]   = (float)sc;
    ssh[tid*2+1] = (float)((double)bt4[tid] - mean*sc);
  }
  __syncthreads();

  int nn = tid & 63;
  int l  = blockIdx.x*4 + (tid >> 6);
  const float* src = y4 + ((size_t)nn*1024 + l)*12;
  #pragma unroll
  for (int c=0;c<12;c++){
    float v = lrelu(fmaf(src[c], ssh[2*c], ssh[2*c+1]));
    hT[((size_t)(c*1024 + l))*64 + nn] = v;
  }
}

// ---------------------------------------------------------------------------
// K5 v4 (proven 88.7us s_load form -- kept as workspace fallback for FC1).
__global__ __launch_bounds__(256) void k_fc2(const float* __restrict__ AT,
    const float* __restrict__ W, float* __restrict__ part,
    int nsplit, int kwave){
  __shared__ float red[64][64];            // 16 KB
  const int lane = threadIdx.x & 63;
  const int w  = __builtin_amdgcn_readfirstlane(threadIdx.x >> 6);
  const int sk = w >> 1;                   // k-split within block (0/1)
  const int mh = (w & 1) * 32;             // m-half base
  const int s  = blockIdx.x % nsplit;
  const int ot = blockIdx.x / nsplit;
  const int o  = ot*64 + lane;
  const int k0 = (s*2 + sk) * kwave;

  float acc[32];
  #pragma unroll
  for (int m=0;m<32;m++) acc[m]=0.f;

  const float* ap = AT + (size_t)k0*64 + mh;
  const float* wp = W  + (size_t)k0*3072 + o;

  float wb[8];
  #pragma unroll
  for (int u=0;u<8;u++) wb[u] = wp[(size_t)u*3072];

  for (int k=0; k<kwave-8; k+=8){
    float wn[8];
    const float* wpn = wp + (size_t)(k+8)*3072;
    #pragma unroll
    for (int u=0;u<8;u++) wn[u] = wpn[(size_t)u*3072];
    #pragma unroll
    for (int u=0;u<8;u++){
      const float* a = ap + (size_t)(k+u)*64;
      #pragma unroll
      for (int m=0;m<32;m++) acc[m] = fmaf(a[m], wb[u], acc[m]);
    }
    #pragma unroll
    for (int u=0;u<8;u++) wb[u] = wn[u];
  }
  #pragma unroll
  for (int u=0;u<8;u++){
    const float* a = ap + (size_t)(kwave-8+u)*64;
    #pragma unroll
    for (int m=0;m<32;m++) acc[m] = fmaf(a[m], wb[u], acc[m]);
  }

  if (sk == 1){
    #pragma unroll
    for (int m=0;m<32;m++) red[mh + m][lane] = acc[m];
  }
  __syncthreads();
  if (sk == 0){
    float* dst = part + (size_t)s*64*3072 + o;
    #pragma unroll
    for (int m=0;m<32;m++){
      acc[m] += red[mh + m][lane];
      dst[(size_t)(mh + m)*3072] = acc[m];
    }
  }
}

// ---------------------------------------------------------------------------
// K5 v9: v4 compute loop, A via whole-panel LDS preload (round-13).
// The ONLY change vs v4: the block's full A panel (2*kwave*64 floats, 48KB
// at kwave=96) is copied to LDS once before the main loop (coalesced float4,
// one barrier, zero in-loop staging machinery -- the v6/v8 allocator lesson),
// and `ap` points at LDS. A reads become uniform-address ds_read_b128
// broadcasts (conflict-free, few-cycle issue) instead of the ~200cy s_load
// chain that capped v4 at 40% duty. Live ranges of stage & compute don't
// overlap -> VGPR stays v4-like. Epilogue red aliases the panel.
// REQUIRES kwave == 96 (static 48KB LDS).
__global__ __launch_bounds__(256) void k_fc6(const float* __restrict__ AT,
    const float* __restrict__ W, float* __restrict__ part,
    int nsplit){
  const int kwave = 96;
  __shared__ float als[2*96*64];           // 48 KB; epilogue reuses head 16KB
  const int tid  = threadIdx.x;
  const int lane = tid & 63;
  const int w  = __builtin_amdgcn_readfirstlane(tid >> 6);
  const int sk = w >> 1;                   // k-split within block (0/1)
  const int mh = (w & 1) * 32;             // m-half base
  const int s  = blockIdx.x % nsplit;
  const int ot = blockIdx.x / nsplit;
  const int o  = ot*64 + lane;
  const int k0 = (s*2 + sk) * kwave;

  // preload the whole A panel (contiguous 2*kwave*64 floats)
  {
    const float4* src = (const float4*)(AT + (size_t)(s*2*kwave)*64);
    float4* dst = (float4*)als;
    #pragma unroll
    for (int i=0;i<12;i++)
      dst[tid + i*256] = src[tid + i*256];
  }
  __syncthreads();

  float acc[32];
  #pragma unroll
  for (int m=0;m<32;m++) acc[m]=0.f;

  const float* ap = als + (sk*kwave)*64 + mh;
  const float* wp = W + (size_t)k0*3072 + o;

  float wb[8];
  #pragma unroll
  for (int u=0;u<8;u++) wb[u] = wp[(size_t)u*3072];

  for (int k=0; k<kwave-8; k+=8){
    float wn[8];
    const float* wpn = wp + (size_t)(k+8)*3072;
    #pragma unroll
    for (int u=0;u<8;u++) wn[u] = wpn[(size_t)u*3072];
    #pragma unroll
    for (int u=0;u<8;u++){
      const float* a = ap + (k+u)*64;
      #pragma unroll
      for (int m=0;m<32;m++) acc[m] = fmaf(a[m], wb[u], acc[m]);
    }
    #pragma unroll
    for (int u=0;u<8;u++) wb[u] = wn[u];
  }
  #pragma unroll
  for (int u=0;u<8;u++){
    const float* a = ap + (kwave-8+u)*64;
    #pragma unroll
    for (int m=0;m<32;m++) acc[m] = fmaf(a[m], wb[u], acc[m]);
  }

  // epilogue: reuse als head as red[64][64]; fixed order sk0 + sk1
  __syncthreads();                         // all panel reads complete
  if (sk == 1){
    #pragma unroll
    for (int m=0;m<32;m++) als[(mh+m)*64 + lane] = acc[m];
  }
  __syncthreads();
  if (sk == 0){
    float* dst = part + (size_t)s*64*3072 + o;
    #pragma unroll
    for (int m=0;m<32;m++){
      acc[m] += als[(mh+m)*64 + lane];
      dst[(size_t)(mh+m)*3072] = acc[m];
    }
  }
}

// ---------------------------------------------------------------------------
// K5r v2: reduce split-K partials [s][m][o] (+bias, optional lrelu),
// optional transpose. Fixed-order s-sum (deterministic).
__global__ __launch_bounds__(256) void k_fcreduce(const float* __restrict__ part,
    const float* __restrict__ bias, float* __restrict__ out,
    int S, int act, int transposed){
  const int ot = blockIdx.x >> 4;       // /16
  const int mg = blockIdx.x & 15;
  const int lane = threadIdx.x & 63;
  const int o = ot*64 + lane;
  const int m = mg*4 + (threadIdx.x >> 6);
  float v = 0.f;
  for (int s=0;s<S;s++) v += part[((size_t)s*64 + m)*3072 + o];
  v += bias[o];
  if (act) v = fmaxf(v, 0.2f*v);
  if (transposed) out[(size_t)o*64 + m] = v;
  else            out[(size_t)m*3072 + o] = v;
}

// ---------------------------------------------------------------------------
// K6: label revise + gumbel + argmax one-hot.  One block per n.
__global__ __launch_bounds__(256) void k_label(const float* __restrict__ logits,
    const float* __restrict__ gumbel, float* __restrict__ out){
  __shared__ int pred[1024];
  const int n = blockIdx.x;
  const float* lg = logits + (size_t)n*3072;
  for (int l = threadIdx.x; l < 1024; l += 256){
    float a = lg[l*3], b = lg[l*3+1], c = lg[l*3+2];
    int pm = 0; float bv = a;
    if (b > bv){ pm = 1; bv = b; }
    if (c > bv){ pm = 2; }
    pred[l] = pm;
  }
  __syncthreads();
  const float* gm = gumbel + (size_t)n*3072;
  float* op = out + (size_t)n*3072;
  for (int l = threadIdx.x; l < 1024; l += 256){
    int phase = l & 3, lb = l >> 2;
    int pb  = pred[lb*4];
    int nxt = (lb < 255) ? pred[(lb+1)*4] : -1;
    bool chain = (pb == 2) && (nxt == 2);
    int prev = (l > 0) ? pred[l-1] : 0;
    bool c100 = (((phase == 1) && (pb == 1 || pb == 2)) ||
                 ((phase == 3) && (prev == 1))) && !chain;
    float r0, r1, r2;
    if (chain && phase != 0){ r0=0.f; r1=0.f; r2=1.f; }
    else if (c100)          { r0=1.f; r1=0.f; r2=0.f; }
    else { r0 = lg[l*3]; r1 = lg[l*3+1]; r2 = lg[l*3+2]; }
    float z0 = r0 + gm[l*3], z1 = r1 + gm[l*3+1], z2 = r2 + gm[l*3+2];
    int am = 0; float bv = z0;
    if (z1 > bv){ am = 1; bv = z1; }
    if (z2 > bv){ am = 2; }
    op[l*3+0] = (am == 0) ? 1.f : 0.f;
    op[l*3+1] = (am == 1) ? 1.f : 0.f;
    op[l*3+2] = (am == 2) ? 1.f : 0.f;
  }
}

// ---------------------------------------------------------------------------
extern "C" void kernel_launch(void* const* d_in, const int* in_sizes, int n_in,
                              void* d_out, int out_size, void* d_ws, size_t ws_size,
                              hipStream_t stream){
  (void)in_sizes; (void)n_in; (void)out_size;
  const float* noise     = (const float*)d_in[0];
  const float* cond_data = (const float*)d_in[1];
  const float* gumbel    = (const float*)d_in[2];
  const float* ew1 = (const float*)d_in[3];
  const float* eb1 = (const float*)d_in[4];
  const float* ew2 = (const float*)d_in[5];
  const float* eb2 = (const float*)d_in[6];
  const float* eg  = (const float*)d_in[7];
  const float* ebt = (const float*)d_in[8];
  const float* w3  = (const float*)d_in[9];
  const float* b3  = (const float*)d_in[10];
  const float* w4  = (const float*)d_in[11];
  const float* b4  = (const float*)d_in[12];
  const float* g4  = (const float*)d_in[13];
  const float* bt4 = (const float*)d_in[14];
  const float* lw1 = (const float*)d_in[15];
  const float* lb1 = (const float*)d_in[16];
  const float* lw2 = (const float*)d_in[17];
  const float* lb2 = (const float*)d_in[18];
  const float* lw3 = (const float*)d_in[19];
  const float* lb3 = (const float*)d_in[20];

  float* ws = (float*)d_ws;
  // workspace layout (float offsets) -- gi buffer eliminated (conv3 fusion)
  float* wT1   = ws + 0;
  float* wT2   = ws + 16448;
  float* wT3   = ws + 17984;
  float* wT4   = ws + 44864;
  float* pe    = ws + 46592;
  float* bn2p  = ws + 128512;
  float* bn4p  = ws + 136736;
  float* x1    = ws + 143360;            // 2,097,152 -> ends 2,240,512
  float* y2    = ws + 2240512;           // 1,048,576 -> ends 3,289,088
  float* h3    = ws + 3289088;           // 3,145,728 -> ends 6,434,816
  float* y4    = ws + 6434816;           //   786,432 -> ends 7,221,248
  float* hT    = ws + 7221248;           //   786,432 -> ends 8,007,680
  float* fcp   = ws + 8007680;           // split-K partials: S1 * 196,608

  // FC1: prefer LDS-panel form (needs kwave=96 -> S1=64 -> 50MB partials);
  // fall back to the proven v4 s_load form at S1=32 if workspace is tight.
  int S1 = 64;
  bool lds_fc1 = true;
  if (ws_size < (size_t)(8007680 + (size_t)64*196608 + 3*196608) * 4){
    S1 = 32; lds_fc1 = false;
  }
  const int S23 = 16;
  float* fc1T  = fcp + (size_t)S1*196608;
  float* fc2T  = fc1T + 196608;
  float* logi  = fc2T + 196608;

  float* out_gen  = (float*)d_out;           // 64*1024*3
  float* out_cond = (float*)d_out + 196608;  // 64*16*1024

  k_init <<<502, 256, 0, stream>>>(ew1, ew2, w3, w4, wT1, wT2, wT3, wT4, pe);
  k_conv1<<<1024, 256, 0, stream>>>(cond_data, wT1, eb1, x1);
  k_conv2<<<256, 256, 0, stream>>>(x1, wT2, eb2, y2, bn2p);
  k_conv3<<<1024, 256, 0, stream>>>(y2, noise, pe, bn2p, eg, ebt, wT3, b3, h3, out_cond);
  k_conv4<<<256, 256, 0, stream>>>(h3, wT4, b4, y4, bn4p);
  k_hflat<<<256, 256, 0, stream>>>(y4, bn4p, g4, bt4, hT);
  if (lds_fc1) k_fc6<<<48*64, 256, 0, stream>>>(hT, lw1, fcp, 64);
  else         k_fc2<<<48*32, 256, 0, stream>>>(hT, lw1, fcp, 32, 192);
  k_fcreduce<<<768, 256, 0, stream>>>(fcp, lb1, fc1T, S1, 1, 1);
  k_fc6  <<<48*16, 256, 0, stream>>>(fc1T, lw2, fcp, 16);
  k_fcreduce<<<768, 256, 0, stream>>>(fcp, lb2, fc2T, S23, 1, 1);
  k_fc6  <<<48*16, 256, 0, stream>>>(fc2T, lw3, fcp, 16);
  k_fcreduce<<<768, 256, 0, stream>>>(fcp, lb3, logi, S23, 0, 0);
  k_label<<<64, 256, 0, stream>>>(logi, gumbel, out_gen);
}

// Round 14
// 349.748 us; speedup vs baseline: 1.0871x; 1.0871x over previous
//
#include <hip/hip_runtime.h>
#include <hip/hip_bf16.h>
#include <math.h>

// Problem constants
// N=64, L=1024, C_IN=514, NOISE_C=64, COMP=16, NC=3, MAIN_C=80
// P = N*L = 65536 positions

__device__ __forceinline__ float lrelu(float x){ return fmaxf(x, 0.2f*x); }

// ---------------------------------------------------------------------------
// K_init: fused weight transposes + positional encoding.
__global__ void k_init(const float* __restrict__ ew1, const float* __restrict__ ew2,
                       const float* __restrict__ w3,  const float* __restrict__ w4,
                       float* __restrict__ wT1, float* __restrict__ wT2,
                       float* __restrict__ wT3, float* __restrict__ wT4,
                       float* __restrict__ pe){
  int i = blockIdx.x*256 + threadIdx.x;
  if (i < 16448){
    int c = i>>5, oc = i&31;
    wT1[i] = ew1[oc*514 + c];
  } else if (i < 16448+1536){
    int j = i - 16448; int oc = j%16; int t = j/16; int dl = t%3; int ic = t/3;
    wT2[j] = ew2[(oc*32+ic)*3 + dl];
  } else if (i < 16448+1536+26880){
    int j = i - 17984; int oc = j%48; int t = j/48; int dl = t%7; int ic = t/7;
    wT3[j] = w3[(oc*80+ic)*7 + dl];
  } else if (i < 46592){
    int j = i - 44864; int oc = j%12; int t = j/12; int dl = t%3; int ic = t/3;
    wT4[j] = w4[(oc*48+ic)*3 + dl];
  } else if (i < 46592 + 80*1024){
    int j = i - 46592;
    int ch = j >> 10, l = j & 1023;
    double dv = 1.0 / pow(10000.0, (2.0*(double)(ch>>1)) / 80.0);
    double ang = dv * (double)l;
    pe[j] = (float)((ch & 1) ? cos(ang) : sin(ang));
  }
}

// ---------------------------------------------------------------------------
// K1 v3: pointwise conv 514->32 + bias + lrelu.  x1[p][32]
__global__ __launch_bounds__(256) void k_conv1(const float* __restrict__ A,
    const float* __restrict__ wT1, const float* __restrict__ eb1,
    float* __restrict__ x1){
  __shared__ float red[32][256];           // [c][s*64 + pos] : 32 KB
  const int tid = threadIdx.x;
  const int pl  = tid & 63;                // position within block
  const int s   = __builtin_amdgcn_readfirstlane(tid >> 6);   // split id
  const int p   = blockIdx.x*64 + pl;

  const int c0 = (s == 0) ? 0 : 130 + (s-1)*128;
  const int c1 = (s == 0) ? 130 : 130 + s*128;

  const float* row = A + (size_t)p*514;
  float acc[32];
  #pragma unroll
  for (int j=0;j<32;j++) acc[j]=0.f;

  #pragma unroll 8
  for (int c=c0;c<c1;c+=2){
    float2 v = *reinterpret_cast<const float2*>(row + c);
    const float* w = wT1 + (size_t)c*32;
    #pragma unroll
    for (int j=0;j<32;j++) acc[j] = fmaf(v.x, w[j],    acc[j]);
    #pragma unroll
    for (int j=0;j<32;j++) acc[j] = fmaf(v.y, w[32+j], acc[j]);
  }

  #pragma unroll
  for (int j=0;j<32;j++) red[j][s*64 + pl] = acc[j];
  __syncthreads();

  float out[8];
  #pragma unroll
  for (int j=0;j<8;j++){
    const int c = s*8 + j;
    float v = (red[c][pl] + red[c][64+pl]) + (red[c][128+pl] + red[c][192+pl]);
    out[j] = lrelu(v + eb1[c]);
  }
  float* dst = x1 + ((size_t)(blockIdx.x*64 + pl))*32 + s*8;
  *(float4*)(dst  ) = make_float4(out[0],out[1],out[2],out[3]);
  *(float4*)(dst+4) = make_float4(out[4],out[5],out[6],out[7]);
}

// ---------------------------------------------------------------------------
// K2: conv k=3, 32->16 (+bias, no act), y2[p][16], and per-block BN partials.
__global__ __launch_bounds__(256) void k_conv2(const float* __restrict__ x1,
    const float* __restrict__ wT2, const float* __restrict__ eb2,
    float* __restrict__ y2, float* __restrict__ part){
  __shared__ float xt[32][264];
  const int tid = threadIdx.x, lane = tid & 63;
  const int wv = __builtin_amdgcn_readfirstlane(tid >> 6);
  const int n = blockIdx.x >> 2, base = (blockIdx.x & 3)*256;

  for (int r = tid; r < 264; r += 256){
    int l = base - 4 + r;
    if (l >= 0 && l < 1024){
      const float* src = x1 + ((size_t)n*1024 + l)*32;
      #pragma unroll
      for (int c=0;c<32;c+=4){
        float4 v = *(const float4*)(src + c);
        xt[c][r]=v.x; xt[c+1][r]=v.y; xt[c+2][r]=v.z; xt[c+3][r]=v.w;
      }
    } else {
      #pragma unroll
      for (int c=0;c<32;c++) xt[c][r] = 0.f;
    }
  }
  __syncthreads();

  const int og = wv*4;
  const int j0 = 4*lane;
  float acc[4][4];
  #pragma unroll
  for (int j=0;j<4;j++){
    #pragma unroll
    for (int p=0;p<4;p++) acc[j][p]=0.f;
  }
  for (int ic=0; ic<32; ic++){
    float xr[12];
    #pragma unroll
    for (int u=0;u<12;u+=4){
      float4 v = *(const float4*)&xt[ic][j0+u];
      xr[u]=v.x; xr[u+1]=v.y; xr[u+2]=v.z; xr[u+3]=v.w;
    }
    const float* wrow = wT2 + ic*48 + og;   // (ic*3+dl)*16 + og
    #pragma unroll
    for (int dl=0;dl<3;dl++){
      #pragma unroll
      for (int j=0;j<4;j++){
        float w = wrow[dl*16 + j];
        #pragma unroll
        for (int p=0;p<4;p++)
          acc[j][p] = fmaf(xr[p+dl+3], w, acc[j][p]);
      }
    }
  }
  float s[4], q[4];
  #pragma unroll
  for (int j=0;j<4;j++){ s[j]=0.f; q[j]=0.f; }
  const int l0 = base + 4*lane;
  #pragma unroll
  for (int p=0;p<4;p++){
    float vv[4];
    #pragma unroll
    for (int j=0;j<4;j++){
      float val = acc[j][p] + eb2[og+j];
      vv[j]=val; s[j]+=val; q[j]+=val*val;
    }
    *(float4*)(y2 + ((size_t)n*1024 + l0 + p)*16 + og) = make_float4(vv[0],vv[1],vv[2],vv[3]);
  }
  #pragma unroll
  for (int off=32; off; off>>=1){
    #pragma unroll
    for (int j=0;j<4;j++){ s[j] += __shfl_xor(s[j], off); q[j] += __shfl_xor(q[j], off); }
  }
  if (lane == 0){
    #pragma unroll
    for (int j=0;j<4;j++){
      part[((size_t)blockIdx.x*16 + og + j)*2    ] = s[j];
      part[((size_t)blockIdx.x*16 + og + j)*2 + 1] = q[j];
    }
  }
}

// ---------------------------------------------------------------------------
// K3 v2: conv k=7, 80->48 + bias + lrelu, with gi construction fused in.
__global__ __launch_bounds__(256) void k_conv3(const float* __restrict__ y2,
    const float* __restrict__ noise, const float* __restrict__ pe,
    const float* __restrict__ bn2p, const float* __restrict__ eg,
    const float* __restrict__ ebt,
    const float* __restrict__ wT3, const float* __restrict__ b3,
    float* __restrict__ h3, float* __restrict__ cond_out){
  __shared__ float xt[80][72];             // 23 KB
  __shared__ double pS[16][16], pQ[16][16];
  __shared__ float ssh[32];
  const int tid = threadIdx.x, lane = tid & 63;
  const int og = __builtin_amdgcn_readfirstlane(tid >> 6) * 12;
  const int n = blockIdx.x >> 4, base = (blockIdx.x & 15)*64;

  // inline BN2 stats (fixed-order fp64, identical in every block)
  {
    int c = tid & 15, chunk = tid >> 4;
    double S=0.0, Q=0.0;
    #pragma unroll 4
    for (int i=chunk*16; i<chunk*16+16; i++){
      S += (double)bn2p[((size_t)i*16 + c)*2];
      Q += (double)bn2p[((size_t)i*16 + c)*2 + 1];
    }
    pS[chunk][c] = S; pQ[chunk][c] = Q;
  }
  __syncthreads();
  if (tid < 16){
    double S=0.0, Q=0.0;
    #pragma unroll
    for (int k=0;k<16;k++){ S += pS[k][tid]; Q += pQ[k][tid]; }
    double mean = S / 65536.0;
    double var  = Q / 65536.0 - mean*mean;
    double sc   = (double)eg[tid] / sqrt(var + 1e-5);
    ssh[tid*2]   = (float)sc;
    ssh[tid*2+1] = (float)((double)ebt[tid] - mean*sc);
  }
  __syncthreads();

  // stage rows 0..71 (l = base-4+r), computing gi values inline
  {
    const int q = tid & 3;               // channel quarter (20 ch each)
    for (int r = tid >> 2; r < 72; r += 64){
      int l = base - 4 + r;
      bool valid = (l >= 0 && l < 1024);
      if (q == 0){
        if (valid){
          size_t p = (size_t)n*1024 + l;
          const float* ys = y2 + p*16;
          bool interior = (r >= 4 && r < 68);
          #pragma unroll
          for (int c=0;c<16;c++){
            float cv = fmaf(ys[c], ssh[2*c], ssh[2*c+1]);
            if (interior) cond_out[((size_t)n*16 + c)*1024 + l] = cv;
            xt[c][r] = cv + pe[c*1024 + l];
          }
          const float* ns = noise + p*64;
          #pragma unroll
          for (int c=0;c<4;c++)
            xt[16+c][r] = ns[c] + pe[(16+c)*1024 + l];
        } else {
          #pragma unroll
          for (int c=0;c<20;c++) xt[c][r] = 0.f;
        }
      } else {
        if (valid){
          size_t p = (size_t)n*1024 + l;
          const float* ns = noise + p*64 + (q*20 - 16);
          #pragma unroll
          for (int c=0;c<20;c++)
            xt[q*20 + c][r] = ns[c] + pe[(q*20 + c)*1024 + l];
        } else {
          #pragma unroll
          for (int c=0;c<20;c++) xt[q*20 + c][r] = 0.f;
        }
      }
    }
  }
  __syncthreads();

  // compute: output pos l = base + lane; input rows lane+1..lane+7
  float acc[12];
  #pragma unroll
  for (int j=0;j<12;j++) acc[j]=0.f;
  for (int ic=0; ic<80; ic++){
    float xr[7];
    #pragma unroll
    for (int u=0;u<7;u++) xr[u] = xt[ic][lane+1+u];
    const float* wrow = wT3 + ic*336 + og;  // (ic*7+dl)*48 + og
    #pragma unroll
    for (int dl=0;dl<7;dl++){
      #pragma unroll
      for (int j=0;j<12;j++)
        acc[j] = fmaf(xr[dl], wrow[dl*48 + j], acc[j]);
    }
  }
  {
    float v[12];
    #pragma unroll
    for (int j=0;j<12;j++) v[j] = lrelu(acc[j] + b3[og+j]);
    float* dst = h3 + ((size_t)n*1024 + base + lane)*48 + og;
    *(float4*)(dst  ) = make_float4(v[0],v[1],v[2],v[3]);
    *(float4*)(dst+4) = make_float4(v[4],v[5],v[6],v[7]);
    *(float4*)(dst+8) = make_float4(v[8],v[9],v[10],v[11]);
  }
}

// ---------------------------------------------------------------------------
// K4: conv k=3, 48->12 (+bias), y4[p][12] + BN partials.
__global__ __launch_bounds__(256) void k_conv4(const float* __restrict__ h3,
    const float* __restrict__ wT4, const float* __restrict__ b4,
    float* __restrict__ y4, float* __restrict__ part){
  __shared__ float xt[48][258];
  __shared__ float red[4][24];
  const int tid = threadIdx.x, lane = tid & 63, wv = tid >> 6;
  const int n = blockIdx.x >> 2, base = (blockIdx.x & 3)*256;

  for (int r = tid; r < 258; r += 256){
    int l = base - 1 + r;
    if (l >= 0 && l < 1024){
      const float* src = h3 + ((size_t)n*1024 + l)*48;
      #pragma unroll
      for (int c=0;c<48;c+=4){
        float4 v = *(const float4*)(src + c);
        xt[c][r]=v.x; xt[c+1][r]=v.y; xt[c+2][r]=v.z; xt[c+3][r]=v.w;
      }
    } else {
      #pragma unroll
      for (int c=0;c<48;c++) xt[c][r]=0.f;
    }
  }
  __syncthreads();

  float acc[12];
  #pragma unroll
  for (int j=0;j<12;j++) acc[j]=0.f;
  for (int ic=0; ic<48; ic++){
    float x0 = xt[ic][tid], x1v = xt[ic][tid+1], x2 = xt[ic][tid+2];
    const float* wrow = wT4 + ic*36;       // (ic*3+dl)*12
    #pragma unroll
    for (int j=0;j<12;j++){
      acc[j] = fmaf(x0,  wrow[j],      acc[j]);
      acc[j] = fmaf(x1v, wrow[12 + j], acc[j]);
      acc[j] = fmaf(x2,  wrow[24 + j], acc[j]);
    }
  }
  float s[12], q[12];
  #pragma unroll
  for (int j=0;j<12;j++){
    float v = acc[j] + b4[j];
    acc[j] = v; s[j] = v; q[j] = v*v;
  }
  {
    float* dst = y4 + ((size_t)n*1024 + base + tid)*12;
    *(float4*)(dst  ) = make_float4(acc[0],acc[1],acc[2],acc[3]);
    *(float4*)(dst+4) = make_float4(acc[4],acc[5],acc[6],acc[7]);
    *(float4*)(dst+8) = make_float4(acc[8],acc[9],acc[10],acc[11]);
  }
  #pragma unroll
  for (int off=32; off; off>>=1){
    #pragma unroll
    for (int j=0;j<12;j++){ s[j] += __shfl_xor(s[j], off); q[j] += __shfl_xor(q[j], off); }
  }
  if (lane == 0){
    #pragma unroll
    for (int j=0;j<12;j++){ red[wv][j] = s[j]; red[wv][12+j] = q[j]; }
  }
  __syncthreads();
  if (tid < 24){
    float v = red[0][tid] + red[1][tid] + red[2][tid] + red[3][tid];
    if (tid < 12) part[((size_t)blockIdx.x*12 + tid)*2] = v;
    else          part[((size_t)blockIdx.x*12 + (tid-12))*2 + 1] = v;
  }
}

// ---------------------------------------------------------------------------
// K5a v2: hflatT[j][n] = lrelu(bn(y4)), j = c*1024 + l (transposed for FC).
__global__ __launch_bounds__(256) void k_hflat(const float* __restrict__ y4,
    const float* __restrict__ bn4p, const float* __restrict__ g4,
    const float* __restrict__ bt4, float* __restrict__ hT){
  __shared__ double pS[16][12], pQ[16][12];
  __shared__ float ssh[24];
  const int tid = threadIdx.x;
  if (tid < 192){
    int c = tid % 12, chunk = tid / 12;
    double S=0.0, Q=0.0;
    #pragma unroll 4
    for (int i=chunk*16; i<chunk*16+16; i++){
      S += (double)bn4p[((size_t)i*12 + c)*2];
      Q += (double)bn4p[((size_t)i*12 + c)*2 + 1];
    }
    pS[chunk][c] = S; pQ[chunk][c] = Q;
  }
  __syncthreads();
  if (tid < 12){
    double S=0.0, Q=0.0;
    #pragma unroll
    for (int k=0;k<16;k++){ S += pS[k][tid]; Q += pQ[k][tid]; }
    double mean = S / 65536.0;
    double var  = Q / 65536.0 - mean*mean;
    double sc   = (double)g4[tid] / sqrt(var + 1e-5);
    ssh[tid*2]   = (float)sc;
    ssh[tid*2+1] = (float)((double)bt4[tid] - mean*sc);
  }
  __syncthreads();

  int nn = tid & 63;
  int l  = blockIdx.x*4 + (tid >> 6);
  const float* src = y4 + ((size_t)nn*1024 + l)*12;
  #pragma unroll
  for (int c=0;c<12;c++){
    float v = lrelu(fmaf(src[c], ssh[2*c], ssh[2*c+1]));
    hT[((size_t)(c*1024 + l))*64 + nn] = v;
  }
}

// ---------------------------------------------------------------------------
// K5 v10 (k_fc7<NPH>): v4 compute loop + PHASED 24KB LDS A-panel.
// Round-13 taught: ds_read-broadcast A improves per-wave duty (21% vs 15%)
// but a 48KB panel caps residency at 3 blocks/CU. v10 uses a 24KB panel
// (2 sk x 48 k x 64 m) reloaded NPH times with the SIMPLE strided copy
// (3 float4/thread per sk, no per-row machinery -- the v6/v8 allocator
// lesson). 6 blocks/CU; compute structure byte-identical to v4.
// kwave = NPH*48 per sk; k-ascending accumulation (deterministic).
template<int NPH>
__global__ __launch_bounds__(256) void k_fc7(const float* __restrict__ AT,
    const float* __restrict__ W, float* __restrict__ part, int nsplit){
  const int kwave = NPH*48;
  __shared__ float als[2*48*64];           // 24 KB; epilogue reuses head 16KB
  const int tid  = threadIdx.x;
  const int lane = tid & 63;
  const int w  = __builtin_amdgcn_readfirstlane(tid >> 6);
  const int sk = w >> 1;                   // k-split within block (0/1)
  const int mh = (w & 1) * 32;             // m-half base
  const int s  = blockIdx.x % nsplit;
  const int ot = blockIdx.x / nsplit;
  const int o  = ot*64 + lane;
  const int k0 = (s*2 + sk) * kwave;

  float acc[32];
  #pragma unroll
  for (int m=0;m<32;m++) acc[m]=0.f;

  const float* wp = W + (size_t)k0*3072 + o;
  float wb[8];
  #pragma unroll
  for (int u=0;u<8;u++) wb[u] = wp[(size_t)u*3072];

  for (int ph=0; ph<NPH; ++ph){
    __syncthreads();                       // previous phase fully consumed
    {
      const float4* s0 = (const float4*)(AT + ((size_t)(s*2    )*kwave + ph*48)*64);
      const float4* s1 = (const float4*)(AT + ((size_t)(s*2 + 1)*kwave + ph*48)*64);
      float4* d = (float4*)als;
      #pragma unroll
      for (int i=0;i<3;i++){
        d[tid + i*256]       = s0[tid + i*256];
        d[768 + tid + i*256] = s1[tid + i*256];
      }
    }
    __syncthreads();

    const float* ap = als + sk*48*64 + mh;
    #pragma unroll
    for (int g=0; g<6; ++g){               // 6 groups of 8 k per phase
      const int kk = ph*48 + g*8;          // k within this sk's range
      float wn[8];
      const bool pref = (kk + 8 < kwave);
      if (pref){
        const float* wpn = wp + (size_t)(kk+8)*3072;
        #pragma unroll
        for (int u=0;u<8;u++) wn[u] = wpn[(size_t)u*3072];
      }
      #pragma unroll
      for (int u=0;u<8;u++){
        const float* a = ap + (g*8+u)*64;
        #pragma unroll
        for (int m=0;m<32;m++) acc[m] = fmaf(a[m], wb[u], acc[m]);
      }
      if (pref){
        #pragma unroll
        for (int u=0;u<8;u++) wb[u] = wn[u];
      }
    }
  }

  // epilogue: reuse als head as red[64][64]; fixed order sk0 + sk1
  __syncthreads();                         // all panel reads complete
  if (sk == 1){
    #pragma unroll
    for (int m=0;m<32;m++) als[(mh+m)*64 + lane] = acc[m];
  }
  __syncthreads();
  if (sk == 0){
    float* dst = part + (size_t)s*64*3072 + o;
    #pragma unroll
    for (int m=0;m<32;m++){
      acc[m] += als[(mh+m)*64 + lane];
      dst[(size_t)(mh+m)*3072] = acc[m];
    }
  }
}

// ---------------------------------------------------------------------------
// K5r v2: reduce split-K partials [s][m][o] (+bias, optional lrelu),
// optional transpose. Fixed-order s-sum (deterministic).
__global__ __launch_bounds__(256) void k_fcreduce(const float* __restrict__ part,
    const float* __restrict__ bias, float* __restrict__ out,
    int S, int act, int transposed){
  const int ot = blockIdx.x >> 4;       // /16
  const int mg = blockIdx.x & 15;
  const int lane = threadIdx.x & 63;
  const int o = ot*64 + lane;
  const int m = mg*4 + (threadIdx.x >> 6);
  float v = 0.f;
  for (int s=0;s<S;s++) v += part[((size_t)s*64 + m)*3072 + o];
  v += bias[o];
  if (act) v = fmaxf(v, 0.2f*v);
  if (transposed) out[(size_t)o*64 + m] = v;
  else            out[(size_t)m*3072 + o] = v;
}

// ---------------------------------------------------------------------------
// K6: label revise + gumbel + argmax one-hot.  One block per n.
__global__ __launch_bounds__(256) void k_label(const float* __restrict__ logits,
    const float* __restrict__ gumbel, float* __restrict__ out){
  __shared__ int pred[1024];
  const int n = blockIdx.x;
  const float* lg = logits + (size_t)n*3072;
  for (int l = threadIdx.x; l < 1024; l += 256){
    float a = lg[l*3], b = lg[l*3+1], c = lg[l*3+2];
    int pm = 0; float bv = a;
    if (b > bv){ pm = 1; bv = b; }
    if (c > bv){ pm = 2; }
    pred[l] = pm;
  }
  __syncthreads();
  const float* gm = gumbel + (size_t)n*3072;
  float* op = out + (size_t)n*3072;
  for (int l = threadIdx.x; l < 1024; l += 256){
    int phase = l & 3, lb = l >> 2;
    int pb  = pred[lb*4];
    int nxt = (lb < 255) ? pred[(lb+1)*4] : -1;
    bool chain = (pb == 2) && (nxt == 2);
    int prev = (l > 0) ? pred[l-1] : 0;
    bool c100 = (((phase == 1) && (pb == 1 || pb == 2)) ||
                 ((phase == 3) && (prev == 1))) && !chain;
    float r0, r1, r2;
    if (chain && phase != 0){ r0=0.f; r1=0.f; r2=1.f; }
    else if (c100)          { r0=1.f; r1=0.f; r2=0.f; }
    else { r0 = lg[l*3]; r1 = lg[l*3+1]; r2 = lg[l*3+2]; }
    float z0 = r0 + gm[l*3], z1 = r1 + gm[l*3+1], z2 = r2 + gm[l*3+2];
    int am = 0; float bv = z0;
    if (z1 > bv){ am = 1; bv = z1; }
    if (z2 > bv){ am = 2; }
    op[l*3+0] = (am == 0) ? 1.f : 0.f;
    op[l*3+1] = (am == 1) ? 1.f : 0.f;
    op[l*3+2] = (am == 2) ? 1.f : 0.f;
  }
}

// ---------------------------------------------------------------------------
extern "C" void kernel_launch(void* const* d_in, const int* in_sizes, int n_in,
                              void* d_out, int out_size, void* d_ws, size_t ws_size,
                              hipStream_t stream){
  (void)in_sizes; (void)n_in; (void)out_size; (void)ws_size;
  const float* noise     = (const float*)d_in[0];
  const float* cond_data = (const float*)d_in[1];
  const float* gumbel    = (const float*)d_in[2];
  const float* ew1 = (const float*)d_in[3];
  const float* eb1 = (const float*)d_in[4];
  const float* ew2 = (const float*)d_in[5];
  const float* eb2 = (const float*)d_in[6];
  const float* eg  = (const float*)d_in[7];
  const float* ebt = (const float*)d_in[8];
  const float* w3  = (const float*)d_in[9];
  const float* b3  = (const float*)d_in[10];
  const float* w4  = (const float*)d_in[11];
  const float* b4  = (const float*)d_in[12];
  const float* g4  = (const float*)d_in[13];
  const float* bt4 = (const float*)d_in[14];
  const float* lw1 = (const float*)d_in[15];
  const float* lb1 = (const float*)d_in[16];
  const float* lw2 = (const float*)d_in[17];
  const float* lb2 = (const float*)d_in[18];
  const float* lw3 = (const float*)d_in[19];
  const float* lb3 = (const float*)d_in[20];

  float* ws = (float*)d_ws;
  // workspace layout (float offsets) -- gi buffer eliminated (conv3 fusion)
  float* wT1   = ws + 0;
  float* wT2   = ws + 16448;
  float* wT3   = ws + 17984;
  float* wT4   = ws + 44864;
  float* pe    = ws + 46592;
  float* bn2p  = ws + 128512;
  float* bn4p  = ws + 136736;
  float* x1    = ws + 143360;            // 2,097,152 -> ends 2,240,512
  float* y2    = ws + 2240512;           // 1,048,576 -> ends 3,289,088
  float* h3    = ws + 3289088;           // 3,145,728 -> ends 6,434,816
  float* y4    = ws + 6434816;           //   786,432 -> ends 7,221,248
  float* hT    = ws + 7221248;           //   786,432 -> ends 8,007,680
  float* fcp   = ws + 8007680;           // split-K partials: 32 * 196,608

  const int S1  = 32;                    // FC1: kwave=192 = 4 phases * 48
  const int S23 = 32;                    // FC2/3: kwave=48 = 1 phase
  float* fc1T  = fcp + (size_t)32*196608;
  float* fc2T  = fc1T + 196608;
  float* logi  = fc2T + 196608;

  float* out_gen  = (float*)d_out;           // 64*1024*3
  float* out_cond = (float*)d_out + 196608;  // 64*16*1024

  k_init <<<502, 256, 0, stream>>>(ew1, ew2, w3, w4, wT1, wT2, wT3, wT4, pe);
  k_conv1<<<1024, 256, 0, stream>>>(cond_data, wT1, eb1, x1);
  k_conv2<<<256, 256, 0, stream>>>(x1, wT2, eb2, y2, bn2p);
  k_conv3<<<1024, 256, 0, stream>>>(y2, noise, pe, bn2p, eg, ebt, wT3, b3, h3, out_cond);
  k_conv4<<<256, 256, 0, stream>>>(h3, wT4, b4, y4, bn4p);
  k_hflat<<<256, 256, 0, stream>>>(y4, bn4p, g4, bt4, hT);
  k_fc7<4><<<48*S1, 256, 0, stream>>>(hT,   lw1, fcp, S1);
  k_fcreduce<<<768, 256, 0, stream>>>(fcp, lb1, fc1T, S1, 1, 1);
  k_fc7<1><<<48*S23, 256, 0, stream>>>(fc1T, lw2, fcp, S23);
  k_fcreduce<<<768, 256, 0, stream>>>(fcp, lb2, fc2T, S23, 1, 1);
  k_fc7<1><<<48*S23, 256, 0, stream>>>(fc2T, lw3, fcp, S23);
  k_fcreduce<<<768, 256, 0, stream>>>(fcp, lb3, logi, S23, 0, 0);
  k_label<<<64, 256, 0, stream>>>(logi, gumbel, out_gen);
}

// Round 15
// 314.631 us; speedup vs baseline: 1.2084x; 1.1116x over previous
//
#include <hip/hip_runtime.h>
#include <hip/hip_bf16.h>
#include <math.h>

// Problem constants
// N=64, L=1024, C_IN=514, NOISE_C=64, COMP=16, NC=3, MAIN_C=80
// P = N*L = 65536 positions

__device__ __forceinline__ float lrelu(float x){ return fmaxf(x, 0.2f*x); }

// ---------------------------------------------------------------------------
// K_init: fused weight transposes + positional encoding.
__global__ void k_init(const float* __restrict__ ew1, const float* __restrict__ ew2,
                       const float* __restrict__ w3,  const float* __restrict__ w4,
                       float* __restrict__ wT1, float* __restrict__ wT2,
                       float* __restrict__ wT3, float* __restrict__ wT4,
                       float* __restrict__ pe){
  int i = blockIdx.x*256 + threadIdx.x;
  if (i < 16448){
    int c = i>>5, oc = i&31;
    wT1[i] = ew1[oc*514 + c];
  } else if (i < 16448+1536){
    int j = i - 16448; int oc = j%16; int t = j/16; int dl = t%3; int ic = t/3;
    wT2[j] = ew2[(oc*32+ic)*3 + dl];
  } else if (i < 16448+1536+26880){
    int j = i - 17984; int oc = j%48; int t = j/48; int dl = t%7; int ic = t/7;
    wT3[j] = w3[(oc*80+ic)*7 + dl];
  } else if (i < 46592){
    int j = i - 44864; int oc = j%12; int t = j/12; int dl = t%3; int ic = t/3;
    wT4[j] = w4[(oc*48+ic)*3 + dl];
  } else if (i < 46592 + 80*1024){
    int j = i - 46592;
    int ch = j >> 10, l = j & 1023;
    double dv = 1.0 / pow(10000.0, (2.0*(double)(ch>>1)) / 80.0);
    double ang = dv * (double)l;
    pe[j] = (float)((ch & 1) ? cos(ang) : sin(ang));
  }
}

// ---------------------------------------------------------------------------
// K1 v3: pointwise conv 514->32 + bias + lrelu.  x1[p][32]
__global__ __launch_bounds__(256) void k_conv1(const float* __restrict__ A,
    const float* __restrict__ wT1, const float* __restrict__ eb1,
    float* __restrict__ x1){
  __shared__ float red[32][256];           // [c][s*64 + pos] : 32 KB
  const int tid = threadIdx.x;
  const int pl  = tid & 63;                // position within block
  const int s   = __builtin_amdgcn_readfirstlane(tid >> 6);   // split id
  const int p   = blockIdx.x*64 + pl;

  const int c0 = (s == 0) ? 0 : 130 + (s-1)*128;
  const int c1 = (s == 0) ? 130 : 130 + s*128;

  const float* row = A + (size_t)p*514;
  float acc[32];
  #pragma unroll
  for (int j=0;j<32;j++) acc[j]=0.f;

  #pragma unroll 8
  for (int c=c0;c<c1;c+=2){
    float2 v = *reinterpret_cast<const float2*>(row + c);
    const float* w = wT1 + (size_t)c*32;
    #pragma unroll
    for (int j=0;j<32;j++) acc[j] = fmaf(v.x, w[j],    acc[j]);
    #pragma unroll
    for (int j=0;j<32;j++) acc[j] = fmaf(v.y, w[32+j], acc[j]);
  }

  #pragma unroll
  for (int j=0;j<32;j++) red[j][s*64 + pl] = acc[j];
  __syncthreads();

  float out[8];
  #pragma unroll
  for (int j=0;j<8;j++){
    const int c = s*8 + j;
    float v = (red[c][pl] + red[c][64+pl]) + (red[c][128+pl] + red[c][192+pl]);
    out[j] = lrelu(v + eb1[c]);
  }
  float* dst = x1 + ((size_t)(blockIdx.x*64 + pl))*32 + s*8;
  *(float4*)(dst  ) = make_float4(out[0],out[1],out[2],out[3]);
  *(float4*)(dst+4) = make_float4(out[4],out[5],out[6],out[7]);
}

// ---------------------------------------------------------------------------
// K2: conv k=3, 32->16 (+bias, no act), y2[p][16], and per-block BN partials.
__global__ __launch_bounds__(256) void k_conv2(const float* __restrict__ x1,
    const float* __restrict__ wT2, const float* __restrict__ eb2,
    float* __restrict__ y2, float* __restrict__ part){
  __shared__ float xt[32][264];
  const int tid = threadIdx.x, lane = tid & 63;
  const int wv = __builtin_amdgcn_readfirstlane(tid >> 6);
  const int n = blockIdx.x >> 2, base = (blockIdx.x & 3)*256;

  for (int r = tid; r < 264; r += 256){
    int l = base - 4 + r;
    if (l >= 0 && l < 1024){
      const float* src = x1 + ((size_t)n*1024 + l)*32;
      #pragma unroll
      for (int c=0;c<32;c+=4){
        float4 v = *(const float4*)(src + c);
        xt[c][r]=v.x; xt[c+1][r]=v.y; xt[c+2][r]=v.z; xt[c+3][r]=v.w;
      }
    } else {
      #pragma unroll
      for (int c=0;c<32;c++) xt[c][r] = 0.f;
    }
  }
  __syncthreads();

  const int og = wv*4;
  const int j0 = 4*lane;
  float acc[4][4];
  #pragma unroll
  for (int j=0;j<4;j++){
    #pragma unroll
    for (int p=0;p<4;p++) acc[j][p]=0.f;
  }
  for (int ic=0; ic<32; ic++){
    float xr[12];
    #pragma unroll
    for (int u=0;u<12;u+=4){
      float4 v = *(const float4*)&xt[ic][j0+u];
      xr[u]=v.x; xr[u+1]=v.y; xr[u+2]=v.z; xr[u+3]=v.w;
    }
    const float* wrow = wT2 + ic*48 + og;   // (ic*3+dl)*16 + og
    #pragma unroll
    for (int dl=0;dl<3;dl++){
      #pragma unroll
      for (int j=0;j<4;j++){
        float w = wrow[dl*16 + j];
        #pragma unroll
        for (int p=0;p<4;p++)
          acc[j][p] = fmaf(xr[p+dl+3], w, acc[j][p]);
      }
    }
  }
  float s[4], q[4];
  #pragma unroll
  for (int j=0;j<4;j++){ s[j]=0.f; q[j]=0.f; }
  const int l0 = base + 4*lane;
  #pragma unroll
  for (int p=0;p<4;p++){
    float vv[4];
    #pragma unroll
    for (int j=0;j<4;j++){
      float val = acc[j][p] + eb2[og+j];
      vv[j]=val; s[j]+=val; q[j]+=val*val;
    }
    *(float4*)(y2 + ((size_t)n*1024 + l0 + p)*16 + og) = make_float4(vv[0],vv[1],vv[2],vv[3]);
  }
  #pragma unroll
  for (int off=32; off; off>>=1){
    #pragma unroll
    for (int j=0;j<4;j++){ s[j] += __shfl_xor(s[j], off); q[j] += __shfl_xor(q[j], off); }
  }
  if (lane == 0){
    #pragma unroll
    for (int j=0;j<4;j++){
      part[((size_t)blockIdx.x*16 + og + j)*2    ] = s[j];
      part[((size_t)blockIdx.x*16 + og + j)*2 + 1] = q[j];
    }
  }
}

// ---------------------------------------------------------------------------
// K3 v2: conv k=7, 80->48 + bias + lrelu, with gi construction fused in.
// (proven rounds 8-14: absmax unchanged; saves ~28 us vs separate k_gi)
__global__ __launch_bounds__(256) void k_conv3(const float* __restrict__ y2,
    const float* __restrict__ noise, const float* __restrict__ pe,
    const float* __restrict__ bn2p, const float* __restrict__ eg,
    const float* __restrict__ ebt,
    const float* __restrict__ wT3, const float* __restrict__ b3,
    float* __restrict__ h3, float* __restrict__ cond_out){
  __shared__ float xt[80][72];             // 23 KB
  __shared__ double pS[16][16], pQ[16][16];
  __shared__ float ssh[32];
  const int tid = threadIdx.x, lane = tid & 63;
  const int og = __builtin_amdgcn_readfirstlane(tid >> 6) * 12;
  const int n = blockIdx.x >> 4, base = (blockIdx.x & 15)*64;

  // inline BN2 stats (fixed-order fp64, identical in every block)
  {
    int c = tid & 15, chunk = tid >> 4;
    double S=0.0, Q=0.0;
    #pragma unroll 4
    for (int i=chunk*16; i<chunk*16+16; i++){
      S += (double)bn2p[((size_t)i*16 + c)*2];
      Q += (double)bn2p[((size_t)i*16 + c)*2 + 1];
    }
    pS[chunk][c] = S; pQ[chunk][c] = Q;
  }
  __syncthreads();
  if (tid < 16){
    double S=0.0, Q=0.0;
    #pragma unroll
    for (int k=0;k<16;k++){ S += pS[k][tid]; Q += pQ[k][tid]; }
    double mean = S / 65536.0;
    double var  = Q / 65536.0 - mean*mean;
    double sc   = (double)eg[tid] / sqrt(var + 1e-5);
    ssh[tid*2]   = (float)sc;
    ssh[tid*2+1] = (float)((double)ebt[tid] - mean*sc);
  }
  __syncthreads();

  // stage rows 0..71 (l = base-4+r), computing gi values inline
  {
    const int q = tid & 3;               // channel quarter (20 ch each)
    for (int r = tid >> 2; r < 72; r += 64){
      int l = base - 4 + r;
      bool valid = (l >= 0 && l < 1024);
      if (q == 0){
        if (valid){
          size_t p = (size_t)n*1024 + l;
          const float* ys = y2 + p*16;
          bool interior = (r >= 4 && r < 68);
          #pragma unroll
          for (int c=0;c<16;c++){
            float cv = fmaf(ys[c], ssh[2*c], ssh[2*c+1]);
            if (interior) cond_out[((size_t)n*16 + c)*1024 + l] = cv;
            xt[c][r] = cv + pe[c*1024 + l];
          }
          const float* ns = noise + p*64;
          #pragma unroll
          for (int c=0;c<4;c++)
            xt[16+c][r] = ns[c] + pe[(16+c)*1024 + l];
        } else {
          #pragma unroll
          for (int c=0;c<20;c++) xt[c][r] = 0.f;
        }
      } else {
        if (valid){
          size_t p = (size_t)n*1024 + l;
          const float* ns = noise + p*64 + (q*20 - 16);
          #pragma unroll
          for (int c=0;c<20;c++)
            xt[q*20 + c][r] = ns[c] + pe[(q*20 + c)*1024 + l];
        } else {
          #pragma unroll
          for (int c=0;c<20;c++) xt[q*20 + c][r] = 0.f;
        }
      }
    }
  }
  __syncthreads();

  // compute: output pos l = base + lane; input rows lane+1..lane+7
  float acc[12];
  #pragma unroll
  for (int j=0;j<12;j++) acc[j]=0.f;
  for (int ic=0; ic<80; ic++){
    float xr[7];
    #pragma unroll
    for (int u=0;u<7;u++) xr[u] = xt[ic][lane+1+u];
    const float* wrow = wT3 + ic*336 + og;  // (ic*7+dl)*48 + og
    #pragma unroll
    for (int dl=0;dl<7;dl++){
      #pragma unroll
      for (int j=0;j<12;j++)
        acc[j] = fmaf(xr[dl], wrow[dl*48 + j], acc[j]);
    }
  }
  {
    float v[12];
    #pragma unroll
    for (int j=0;j<12;j++) v[j] = lrelu(acc[j] + b3[og+j]);
    float* dst = h3 + ((size_t)n*1024 + base + lane)*48 + og;
    *(float4*)(dst  ) = make_float4(v[0],v[1],v[2],v[3]);
    *(float4*)(dst+4) = make_float4(v[4],v[5],v[6],v[7]);
    *(float4*)(dst+8) = make_float4(v[8],v[9],v[10],v[11]);
  }
}

// ---------------------------------------------------------------------------
// K4: conv k=3, 48->12 (+bias), y4[p][12] + BN partials.
__global__ __launch_bounds__(256) void k_conv4(const float* __restrict__ h3,
    const float* __restrict__ wT4, const float* __restrict__ b4,
    float* __restrict__ y4, float* __restrict__ part){
  __shared__ float xt[48][258];
  __shared__ float red[4][24];
  const int tid = threadIdx.x, lane = tid & 63, wv = tid >> 6;
  const int n = blockIdx.x >> 2, base = (blockIdx.x & 3)*256;

  for (int r = tid; r < 258; r += 256){
    int l = base - 1 + r;
    if (l >= 0 && l < 1024){
      const float* src = h3 + ((size_t)n*1024 + l)*48;
      #pragma unroll
      for (int c=0;c<48;c+=4){
        float4 v = *(const float4*)(src + c);
        xt[c][r]=v.x; xt[c+1][r]=v.y; xt[c+2][r]=v.z; xt[c+3][r]=v.w;
      }
    } else {
      #pragma unroll
      for (int c=0;c<48;c++) xt[c][r]=0.f;
    }
  }
  __syncthreads();

  float acc[12];
  #pragma unroll
  for (int j=0;j<12;j++) acc[j]=0.f;
  for (int ic=0; ic<48; ic++){
    float x0 = xt[ic][tid], x1v = xt[ic][tid+1], x2 = xt[ic][tid+2];
    const float* wrow = wT4 + ic*36;       // (ic*3+dl)*12
    #pragma unroll
    for (int j=0;j<12;j++){
      acc[j] = fmaf(x0,  wrow[j],      acc[j]);
      acc[j] = fmaf(x1v, wrow[12 + j], acc[j]);
      acc[j] = fmaf(x2,  wrow[24 + j], acc[j]);
    }
  }
  float s[12], q[12];
  #pragma unroll
  for (int j=0;j<12;j++){
    float v = acc[j] + b4[j];
    acc[j] = v; s[j] = v; q[j] = v*v;
  }
  {
    float* dst = y4 + ((size_t)n*1024 + base + tid)*12;
    *(float4*)(dst  ) = make_float4(acc[0],acc[1],acc[2],acc[3]);
    *(float4*)(dst+4) = make_float4(acc[4],acc[5],acc[6],acc[7]);
    *(float4*)(dst+8) = make_float4(acc[8],acc[9],acc[10],acc[11]);
  }
  #pragma unroll
  for (int off=32; off; off>>=1){
    #pragma unroll
    for (int j=0;j<12;j++){ s[j] += __shfl_xor(s[j], off); q[j] += __shfl_xor(q[j], off); }
  }
  if (lane == 0){
    #pragma unroll
    for (int j=0;j<12;j++){ red[wv][j] = s[j]; red[wv][12+j] = q[j]; }
  }
  __syncthreads();
  if (tid < 24){
    float v = red[0][tid] + red[1][tid] + red[2][tid] + red[3][tid];
    if (tid < 12) part[((size_t)blockIdx.x*12 + tid)*2] = v;
    else          part[((size_t)blockIdx.x*12 + (tid-12))*2 + 1] = v;
  }
}

// ---------------------------------------------------------------------------
// K5a v2: hflatT[j][n] = lrelu(bn(y4)), j = c*1024 + l (transposed for FC).
__global__ __launch_bounds__(256) void k_hflat(const float* __restrict__ y4,
    const float* __restrict__ bn4p, const float* __restrict__ g4,
    const float* __restrict__ bt4, float* __restrict__ hT){
  __shared__ double pS[16][12], pQ[16][12];
  __shared__ float ssh[24];
  const int tid = threadIdx.x;
  if (tid < 192){
    int c = tid % 12, chunk = tid / 12;
    double S=0.0, Q=0.0;
    #pragma unroll 4
    for (int i=chunk*16; i<chunk*16+16; i++){
      S += (double)bn4p[((size_t)i*12 + c)*2];
      Q += (double)bn4p[((size_t)i*12 + c)*2 + 1];
    }
    pS[chunk][c] = S; pQ[chunk][c] = Q;
  }
  __syncthreads();
  if (tid < 12){
    double S=0.0, Q=0.0;
    #pragma unroll
    for (int k=0;k<16;k++){ S += pS[k][tid]; Q += pQ[k][tid]; }
    double mean = S / 65536.0;
    double var  = Q / 65536.0 - mean*mean;
    double sc   = (double)g4[tid] / sqrt(var + 1e-5);
    ssh[tid*2]   = (float)sc;
    ssh[tid*2+1] = (float)((double)bt4[tid] - mean*sc);
  }
  __syncthreads();

  int nn = tid & 63;
  int l  = blockIdx.x*4 + (tid >> 6);
  const float* src = y4 + ((size_t)nn*1024 + l)*12;
  #pragma unroll
  for (int c=0;c<12;c++){
    float v = lrelu(fmaf(src[c], ssh[2*c], ssh[2*c+1]));
    hT[((size_t)(c*1024 + l))*64 + nn] = v;
  }
}

// ---------------------------------------------------------------------------
// K5 v4 (FINAL -- the proven form; 7 restructurings all lost to it).
// 4 waves = 2 k-splits x 2 m-halves, acc[32]/lane, 8-deep W register
// pipeline, A rows via wave-uniform s_loads. kwave multiple of 8, >= 16.
__global__ __launch_bounds__(256) void k_fc2(const float* __restrict__ AT,
    const float* __restrict__ W, float* __restrict__ part,
    int nsplit, int kwave){
  __shared__ float red[64][64];            // 16 KB
  const int lane = threadIdx.x & 63;
  const int w  = __builtin_amdgcn_readfirstlane(threadIdx.x >> 6);
  const int sk = w >> 1;                   // k-split within block (0/1)
  const int mh = (w & 1) * 32;             // m-half base
  const int s  = blockIdx.x % nsplit;
  const int ot = blockIdx.x / nsplit;
  const int o  = ot*64 + lane;
  const int k0 = (s*2 + sk) * kwave;

  float acc[32];
  #pragma unroll
  for (int m=0;m<32;m++) acc[m]=0.f;

  const float* ap = AT + (size_t)k0*64 + mh;
  const float* wp = W  + (size_t)k0*3072 + o;

  float wb[8];
  #pragma unroll
  for (int u=0;u<8;u++) wb[u] = wp[(size_t)u*3072];

  for (int k=0; k<kwave-8; k+=8){
    float wn[8];
    const float* wpn = wp + (size_t)(k+8)*3072;
    #pragma unroll
    for (int u=0;u<8;u++) wn[u] = wpn[(size_t)u*3072];
    #pragma unroll
    for (int u=0;u<8;u++){
      const float* a = ap + (size_t)(k+u)*64;
      #pragma unroll
      for (int m=0;m<32;m++) acc[m] = fmaf(a[m], wb[u], acc[m]);
    }
    #pragma unroll
    for (int u=0;u<8;u++) wb[u] = wn[u];
  }
  #pragma unroll
  for (int u=0;u<8;u++){
    const float* a = ap + (size_t)(kwave-8+u)*64;
    #pragma unroll
    for (int m=0;m<32;m++) acc[m] = fmaf(a[m], wb[u], acc[m]);
  }

  // combine the two k-splits: final = sk0 + sk1 (fixed order, deterministic)
  if (sk == 1){
    #pragma unroll
    for (int m=0;m<32;m++) red[mh + m][lane] = acc[m];
  }
  __syncthreads();
  if (sk == 0){
    float* dst = part + (size_t)s*64*3072 + o;
    #pragma unroll
    for (int m=0;m<32;m++){
      acc[m] += red[mh + m][lane];
      dst[(size_t)(mh + m)*3072] = acc[m];
    }
  }
}

// ---------------------------------------------------------------------------
// K5r v2: reduce split-K partials [s][m][o] (+bias, optional lrelu),
// optional transpose. Fixed-order s-sum (deterministic).
__global__ __launch_bounds__(256) void k_fcreduce(const float* __restrict__ part,
    const float* __restrict__ bias, float* __restrict__ out,
    int S, int act, int transposed){
  const int ot = blockIdx.x >> 4;       // /16
  const int mg = blockIdx.x & 15;
  const int lane = threadIdx.x & 63;
  const int o = ot*64 + lane;
  const int m = mg*4 + (threadIdx.x >> 6);
  float v = 0.f;
  for (int s=0;s<S;s++) v += part[((size_t)s*64 + m)*3072 + o];
  v += bias[o];
  if (act) v = fmaxf(v, 0.2f*v);
  if (transposed) out[(size_t)o*64 + m] = v;
  else            out[(size_t)m*3072 + o] = v;
}

// ---------------------------------------------------------------------------
// K6: label revise + gumbel + argmax one-hot.  One block per n.
__global__ __launch_bounds__(256) void k_label(const float* __restrict__ logits,
    const float* __restrict__ gumbel, float* __restrict__ out){
  __shared__ int pred[1024];
  const int n = blockIdx.x;
  const float* lg = logits + (size_t)n*3072;
  for (int l = threadIdx.x; l < 1024; l += 256){
    float a = lg[l*3], b = lg[l*3+1], c = lg[l*3+2];
    int pm = 0; float bv = a;
    if (b > bv){ pm = 1; bv = b; }
    if (c > bv){ pm = 2; }
    pred[l] = pm;
  }
  __syncthreads();
  const float* gm = gumbel + (size_t)n*3072;
  float* op = out + (size_t)n*3072;
  for (int l = threadIdx.x; l < 1024; l += 256){
    int phase = l & 3, lb = l >> 2;
    int pb  = pred[lb*4];
    int nxt = (lb < 255) ? pred[(lb+1)*4] : -1;
    bool chain = (pb == 2) && (nxt == 2);
    int prev = (l > 0) ? pred[l-1] : 0;
    bool c100 = (((phase == 1) && (pb == 1 || pb == 2)) ||
                 ((phase == 3) && (prev == 1))) && !chain;
    float r0, r1, r2;
    if (chain && phase != 0){ r0=0.f; r1=0.f; r2=1.f; }
    else if (c100)          { r0=1.f; r1=0.f; r2=0.f; }
    else { r0 = lg[l*3]; r1 = lg[l*3+1]; r2 = lg[l*3+2]; }
    float z0 = r0 + gm[l*3], z1 = r1 + gm[l*3+1], z2 = r2 + gm[l*3+2];
    int am = 0; float bv = z0;
    if (z1 > bv){ am = 1; bv = z1; }
    if (z2 > bv){ am = 2; }
    op[l*3+0] = (am == 0) ? 1.f : 0.f;
    op[l*3+1] = (am == 1) ? 1.f : 0.f;
    op[l*3+2] = (am == 2) ? 1.f : 0.f;
  }
}

// ---------------------------------------------------------------------------
extern "C" void kernel_launch(void* const* d_in, const int* in_sizes, int n_in,
                              void* d_out, int out_size, void* d_ws, size_t ws_size,
                              hipStream_t stream){
  (void)in_sizes; (void)n_in; (void)out_size; (void)ws_size;
  const float* noise     = (const float*)d_in[0];
  const float* cond_data = (const float*)d_in[1];
  const float* gumbel    = (const float*)d_in[2];
  const float* ew1 = (const float*)d_in[3];
  const float* eb1 = (const float*)d_in[4];
  const float* ew2 = (const float*)d_in[5];
  const float* eb2 = (const float*)d_in[6];
  const float* eg  = (const float*)d_in[7];
  const float* ebt = (const float*)d_in[8];
  const float* w3  = (const float*)d_in[9];
  const float* b3  = (const float*)d_in[10];
  const float* w4  = (const float*)d_in[11];
  const float* b4  = (const float*)d_in[12];
  const float* g4  = (const float*)d_in[13];
  const float* bt4 = (const float*)d_in[14];
  const float* lw1 = (const float*)d_in[15];
  const float* lb1 = (const float*)d_in[16];
  const float* lw2 = (const float*)d_in[17];
  const float* lb2 = (const float*)d_in[18];
  const float* lw3 = (const float*)d_in[19];
  const float* lb3 = (const float*)d_in[20];

  float* ws = (float*)d_ws;
  // workspace layout (float offsets) -- gi buffer eliminated (conv3 fusion)
  float* wT1   = ws + 0;
  float* wT2   = ws + 16448;
  float* wT3   = ws + 17984;
  float* wT4   = ws + 44864;
  float* pe    = ws + 46592;
  float* bn2p  = ws + 128512;
  float* bn4p  = ws + 136736;
  float* x1    = ws + 143360;            // 2,097,152 -> ends 2,240,512
  float* y2    = ws + 2240512;           // 1,048,576 -> ends 3,289,088
  float* h3    = ws + 3289088;           // 3,145,728 -> ends 6,434,816
  float* y4    = ws + 6434816;           //   786,432 -> ends 7,221,248
  float* hT    = ws + 7221248;           //   786,432 -> ends 8,007,680
  float* fcp   = ws + 8007680;           // split-K partials: 32 * 196,608

  const int S1  = 32;                    // FC1: kwave = 192
  const int S23 = 32;                    // FC2/3: kwave = 48 (6 blocks/CU)
  float* fc1T  = fcp + (size_t)32*196608;
  float* fc2T  = fc1T + 196608;
  float* logi  = fc2T + 196608;
  const int kw1  = 12288 / (S1*2);           // 192
  const int kw23 = 3072 / (S23*2);           // 48

  float* out_gen  = (float*)d_out;           // 64*1024*3
  float* out_cond = (float*)d_out + 196608;  // 64*16*1024

  k_init <<<502, 256, 0, stream>>>(ew1, ew2, w3, w4, wT1, wT2, wT3, wT4, pe);
  k_conv1<<<1024, 256, 0, stream>>>(cond_data, wT1, eb1, x1);
  k_conv2<<<256, 256, 0, stream>>>(x1, wT2, eb2, y2, bn2p);
  k_conv3<<<1024, 256, 0, stream>>>(y2, noise, pe, bn2p, eg, ebt, wT3, b3, h3, out_cond);
  k_conv4<<<256, 256, 0, stream>>>(h3, wT4, b4, y4, bn4p);
  k_hflat<<<256, 256, 0, stream>>>(y4, bn4p, g4, bt4, hT);
  k_fc2  <<<48*S1, 256, 0, stream>>>(hT,   lw1, fcp, S1, kw1);
  k_fcreduce<<<768, 256, 0, stream>>>(fcp, lb1, fc1T, S1, 1, 1);
  k_fc2  <<<48*S23, 256, 0, stream>>>(fc1T, lw2, fcp, S23, kw23);
  k_fcreduce<<<768, 256, 0, stream>>>(fcp, lb2, fc2T, S23, 1, 1);
  k_fc2  <<<48*S23, 256, 0, stream>>>(fc2T, lw3, fcp, S23, kw23);
  k_fcreduce<<<768, 256, 0, stream>>>(fcp, lb3, logi, S23, 0, 0);
  k_label<<<64, 256, 0, stream>>>(logi, gumbel, out_gen);
}